// Round 5
// baseline (29457.309 us; speedup 1.0000x reference)
//
#include <hip/hip_runtime.h>
#include <hip/hip_fp16.h>

// GRU-D 2-layer recurrent head, MI355X.
// Design R5 = R4 + latency hiding. R4 measured 12.5us/step vs ~8.9us/step
// per-CU L2-port floor (1.33MB/step at ~150GB/s/CU), VALUBusy 37%, VGPR 60.
// Changes (numerics identical to R4):
//  - per phase: ALL weight loads issued as a batch (full unroll, arrays with
//    compile-time indices), dots after -> one deep vmcnt window per phase
//    instead of unroll-4 chunks of load/wait/compute.
//  - P2's 25 weight words issued BEFORE the P0/P1 barrier region (no LDS dep).
//  - next-t inputs (x/mask/delta/xl) prefetched into registers one step ahead.

#define BB  256
#define TT  512
#define DX  64
#define EE  32
#define DIN 96
#define HH  256

// packed half-weight offsets (in halves); region layout [K/32][256][4][8]
#define OFF_W0X_R 0        // K=96 regions: 3 segs * 8192
#define OFF_W0X_Z 24576
#define OFF_W0X_H 49152
#define OFF_W0H_R 73728    // K=256 regions: 8 segs * 8192
#define OFF_W0H_Z 139264
#define OFF_W0H_H 204800
#define OFF_W1X_R 270336
#define OFF_W1X_Z 335872
#define OFF_W1X_H 401408
#define OFF_W1H_R 466944
#define OFF_W1H_Z 532480
#define OFF_W1H_H 598016
#define PACK_TOTAL 663552  // halves = 1.33 MB

typedef _Float16 half2_t __attribute__((ext_vector_type(2)));

__global__ void pack_weights(const float* __restrict__ Wr0, const float* __restrict__ Wz0,
                             const float* __restrict__ Wh0, const float* __restrict__ Wr1,
                             const float* __restrict__ Wz1, const float* __restrict__ Wh1,
                             __half* __restrict__ dst) {
  int idx = blockIdx.x * blockDim.x + threadIdx.x;
  if (idx >= PACK_TOTAL) return;
  const float* src;
  int row0, local;
  if (idx < 73728) {                       // x-part of layer0: K=96
    int r = idx / 24576; local = idx % 24576;
    src = (r == 0) ? Wr0 : (r == 1) ? Wz0 : Wh0;
    row0 = 0;
  } else {
    int q = (idx - 73728) / 65536; local = (idx - 73728) % 65536;
    if (q < 3)      { src = (q == 0) ? Wr0 : (q == 1) ? Wz0 : Wh0; row0 = 96;  }
    else if (q < 6) { src = (q == 3) ? Wr1 : (q == 4) ? Wz1 : Wh1; row0 = 0;   }
    else            { src = (q == 6) ? Wr1 : (q == 7) ? Wz1 : Wh1; row0 = 256; }
  }
  // region layout: [seg][j:256][s:4][i:8]; source K-row = seg*32 + s*8 + i
  int seg = local >> 13;
  int rem = local & 8191;
  int j   = rem >> 5;
  int s   = (rem >> 3) & 3;
  int i   = rem & 7;
  int row = row0 + seg * 32 + s * 8 + i;
  dst[idx] = __float2half(src[(size_t)row * HH + j]);
}

__device__ __forceinline__ float dot8(uint4 w, uint4 v, float acc) {
#if __has_builtin(__builtin_amdgcn_fdot2)
  union { uint4 u; half2_t h[4]; } W, V;
  W.u = w; V.u = v;
  acc = __builtin_amdgcn_fdot2(W.h[0], V.h[0], acc, false);
  acc = __builtin_amdgcn_fdot2(W.h[1], V.h[1], acc, false);
  acc = __builtin_amdgcn_fdot2(W.h[2], V.h[2], acc, false);
  acc = __builtin_amdgcn_fdot2(W.h[3], V.h[3], acc, false);
#else
  union { unsigned u; __half2 h; } cw, cv;
  float2 wf, vf;
  cw.u = w.x; cv.u = v.x; wf = __half22float2(cw.h); vf = __half22float2(cv.h);
  acc = fmaf(wf.x, vf.x, acc); acc = fmaf(wf.y, vf.y, acc);
  cw.u = w.y; cv.u = v.y; wf = __half22float2(cw.h); vf = __half22float2(cv.h);
  acc = fmaf(wf.x, vf.x, acc); acc = fmaf(wf.y, vf.y, acc);
  cw.u = w.z; cv.u = v.z; wf = __half22float2(cw.h); vf = __half22float2(cv.h);
  acc = fmaf(wf.x, vf.x, acc); acc = fmaf(wf.y, vf.y, acc);
  cw.u = w.w; cv.u = v.w; wf = __half22float2(cw.h); vf = __half22float2(cv.h);
  acc = fmaf(wf.x, vf.x, acc); acc = fmaf(wf.y, vf.y, acc);
#endif
  return acc;
}

__device__ __forceinline__ float kred(float a) {   // combine 4 K-split partials
  a += __shfl_xor(a, 1, 64);
  a += __shfl_xor(a, 2, 64);
  return a;
}

__device__ __forceinline__ float sigm(float x) { return 1.f / (1.f + __expf(-x)); }

__global__ __launch_bounds__(1024) void grud_fused(
    const float* __restrict__ x, const float* __restrict__ mask,
    const float* __restrict__ delta, const float* __restrict__ xl,
    const int* __restrict__ sidx, const float* __restrict__ emb,
    const float* __restrict__ gx0, const float* __restrict__ gh0,
    const float* __restrict__ br0, const float* __restrict__ bz0, const float* __restrict__ bh0,
    const float* __restrict__ br1, const float* __restrict__ bz1, const float* __restrict__ bh1,
    const float* __restrict__ Wp1, const float* __restrict__ bp1,
    const float* __restrict__ Wp2, const float* __restrict__ bp2,
    const __half* __restrict__ PW, float* __restrict__ out)
{
  const int b   = blockIdx.x;
  const int tid = threadIdx.x;
  const int j   = tid >> 2;      // hidden column 0..255
  const int s   = tid & 3;       // K-split 0..3
  const int s8  = s * 8;         // half-offset of this split's slice in a segment
  const int jb  = j * 4 + s;     // uint4 index within a segment

  __shared__ __align__(16) __half xfh[DIN];    // x_filled (fp16, for dots)
  __shared__ __align__(16) __half hdech[HH];   // h_decay * h0_prev
  __shared__ __align__(16) __half rhh[HH];     // r * h_dec (reused by both layers)
  __shared__ __align__(16) __half h0h[HH];
  __shared__ __align__(16) __half h1h[HH];
  __shared__ float h1f[HH];
  __shared__ float p1f[HH];
  __shared__ float sdel;

  const float brj0 = br0[j], bzj0 = bz0[j], bhj0 = bh0[j];
  const float brj1 = br1[j], bzj1 = bz1[j], bhj1 = bh1[j];
  const float gh0j = gh0[j];
  float gx0j = 0.f;
  if (tid < DX) gx0j = gx0[tid];

  if (tid < HH) { h0h[tid] = __float2half(0.f); h1h[tid] = __float2half(0.f); }
  if (tid < EE) xfh[DX + tid] = __float2half(emb[(size_t)sidx[b] * EE + tid]); // const over t
  float h0j = 0.f, h1j = 0.f;

  const size_t xoff = (size_t)b * TT * DX;
  const uint4* W0XR = reinterpret_cast<const uint4*>(PW + OFF_W0X_R);
  const uint4* W0XZ = reinterpret_cast<const uint4*>(PW + OFF_W0X_Z);
  const uint4* W0XH = reinterpret_cast<const uint4*>(PW + OFF_W0X_H);
  const uint4* W0HR = reinterpret_cast<const uint4*>(PW + OFF_W0H_R);
  const uint4* W0HZ = reinterpret_cast<const uint4*>(PW + OFF_W0H_Z);
  const uint4* W0HH = reinterpret_cast<const uint4*>(PW + OFF_W0H_H);
  const uint4* W1XR = reinterpret_cast<const uint4*>(PW + OFF_W1X_R);
  const uint4* W1XZ = reinterpret_cast<const uint4*>(PW + OFF_W1X_Z);
  const uint4* W1XH = reinterpret_cast<const uint4*>(PW + OFF_W1X_H);
  const uint4* W1HR = reinterpret_cast<const uint4*>(PW + OFF_W1H_R);
  const uint4* W1HZ = reinterpret_cast<const uint4*>(PW + OFF_W1H_Z);
  const uint4* W1HH = reinterpret_cast<const uint4*>(PW + OFF_W1H_H);

  // prefetch t=0 inputs
  float xv = 0.f, mv = 0.f, dv = 0.f, xlv = 0.f;
  if (tid < DX) {
    size_t a = xoff + tid;
    xv = x[a]; mv = mask[a]; dv = delta[a]; xlv = xl[a];
  }
  __syncthreads();

  for (int t = 0; t < TT; ++t) {
    // ---- issue P2 weight loads early (no LDS dependence; covered by P0/P1) ----
    uint4 wa[9];                   // x-part: R0..2, Z0..2, H0..2
    #pragma unroll
    for (int g = 0; g < 3; ++g) {
      wa[g]     = W0XR[g * 1024 + jb];
      wa[3 + g] = W0XZ[g * 1024 + jb];
      wa[6 + g] = W0XH[g * 1024 + jb];
    }
    uint4 wb[16];                  // h-part: R0..7, Z0..7
    #pragma unroll
    for (int g = 0; g < 8; ++g) {
      wb[g]     = W0HR[g * 1024 + jb];
      wb[8 + g] = W0HZ[g * 1024 + jb];
    }

    // ---- P0: x_filled (wave 0, from prefetched regs) + mean-delta scalar ----
    if (tid < DX) {
      float xd = __expf(-fmaxf(dv * gx0j, 0.f)) * xlv;
      xfh[tid] = __float2half(mv > 0.f ? xv : xd);
      float ssum = dv;
      #pragma unroll
      for (int o = 32; o > 0; o >>= 1) ssum += __shfl_down(ssum, o, 64);
      if (tid == 0) sdel = ssum * (1.f / 96.f);
    }
    __syncthreads();
    // ---- P1: h_dec = exp(-relu(sdel*gh0)) * h0 (redundant across s) ----
    float hd = __expf(-fmaxf(sdel * gh0j, 0.f));
    float hdecj = hd * h0j;
    if (s == 0) hdech[j] = __float2half(hdecj);
    __syncthreads();

    // ---- prefetch inputs for t+1 (off critical path) ----
    if (tid < DX && t + 1 < TT) {
      size_t a = xoff + (size_t)(t + 1) * DX + tid;
      xv = x[a]; mv = mask[a]; dv = delta[a]; xlv = xl[a];
    }

    // ---- P2: layer0 r,z pre-acts + x-part of h_tilde ----
    uint4 vx[3], vh[8];
    #pragma unroll
    for (int g = 0; g < 3; ++g) vx[g] = *reinterpret_cast<const uint4*>(xfh + g * 32 + s8);
    #pragma unroll
    for (int g = 0; g < 8; ++g) vh[g] = *reinterpret_cast<const uint4*>(hdech + g * 32 + s8);
    float ar = 0.f, az = 0.f, ah = 0.f;
    #pragma unroll
    for (int g = 0; g < 3; ++g) {
      ar = dot8(wa[g], vx[g], ar);
      az = dot8(wa[3 + g], vx[g], az);
      ah = dot8(wa[6 + g], vx[g], ah);
    }
    #pragma unroll
    for (int g = 0; g < 8; ++g) {
      ar = dot8(wb[g], vh[g], ar);
      az = dot8(wb[8 + g], vh[g], az);
    }
    ar = kred(ar) + brj0;
    az = kred(az) + bzj0;
    float r = sigm(ar);
    float z = sigm(az);
    if (s == 0) rhh[j] = __float2half(r * hdecj);
    __syncthreads();

    // ---- P3: layer0 h_tilde, h0 update ----
    uint4 wc[8];
    #pragma unroll
    for (int g = 0; g < 8; ++g) wc[g] = W0HH[g * 1024 + jb];
    uint4 vr[8];
    #pragma unroll
    for (int g = 0; g < 8; ++g) vr[g] = *reinterpret_cast<const uint4*>(rhh + g * 32 + s8);
    #pragma unroll
    for (int g = 0; g < 8; ++g) ah = dot8(wc[g], vr[g], ah);
    ah = kred(ah) + bhj0;
    float ht = tanhf(ah);
    h0j = (1.f - z) * hdecj + z * ht;
    if (s == 0) h0h[j] = __float2half(h0j);
    __syncthreads();

    // ---- P4: layer1 r,z pre-acts + h0-part of h_tilde ----
    uint4 v0[8], v1[8];
    #pragma unroll
    for (int g = 0; g < 8; ++g) v0[g] = *reinterpret_cast<const uint4*>(h0h + g * 32 + s8);
    #pragma unroll
    for (int g = 0; g < 8; ++g) v1[g] = *reinterpret_cast<const uint4*>(h1h + g * 32 + s8);
    float ar1 = 0.f, az1 = 0.f, ah1 = 0.f;
    {
      uint4 wd[16];                // XR, HR
      #pragma unroll
      for (int g = 0; g < 8; ++g) { wd[g] = W1XR[g * 1024 + jb]; wd[8 + g] = W1HR[g * 1024 + jb]; }
      #pragma unroll
      for (int g = 0; g < 8; ++g) { ar1 = dot8(wd[g], v0[g], ar1); ar1 = dot8(wd[8 + g], v1[g], ar1); }
    }
    {
      uint4 we[16];                // XZ, HZ
      #pragma unroll
      for (int g = 0; g < 8; ++g) { we[g] = W1XZ[g * 1024 + jb]; we[8 + g] = W1HZ[g * 1024 + jb]; }
      #pragma unroll
      for (int g = 0; g < 8; ++g) { az1 = dot8(we[g], v0[g], az1); az1 = dot8(we[8 + g], v1[g], az1); }
    }
    {
      uint4 wf[8];                 // XH
      #pragma unroll
      for (int g = 0; g < 8; ++g) wf[g] = W1XH[g * 1024 + jb];
      #pragma unroll
      for (int g = 0; g < 8; ++g) ah1 = dot8(wf[g], v0[g], ah1);
    }
    ar1 = kred(ar1) + brj1;
    az1 = kred(az1) + bzj1;
    float r1 = sigm(ar1);
    float z1 = sigm(az1);
    if (s == 0) rhh[j] = __float2half(r1 * h1j);
    __syncthreads();

    // ---- P5: layer1 h_tilde, h1 update (no trailing barrier needed) ----
    uint4 wg[8];
    #pragma unroll
    for (int g = 0; g < 8; ++g) wg[g] = W1HH[g * 1024 + jb];
    uint4 vr1[8];
    #pragma unroll
    for (int g = 0; g < 8; ++g) vr1[g] = *reinterpret_cast<const uint4*>(rhh + g * 32 + s8);
    #pragma unroll
    for (int g = 0; g < 8; ++g) ah1 = dot8(wg[g], vr1[g], ah1);
    ah1 = kred(ah1) + bhj1;
    float ht1 = tanhf(ah1);
    h1j = (1.f - z1) * h1j + z1 * ht1;
    if (s == 0) h1h[j] = __float2half(h1j);
  }

  // ---- head: out = relu(h1 @ Wp1 + bp1) @ Wp2 + bp2, fp32, K-split too ----
  if (s == 0) h1f[j] = h1j;
  __syncthreads();
  {
    float a1 = 0.f;
    int k0 = s * 64;
    #pragma unroll 8
    for (int k = 0; k < 64; ++k) a1 = fmaf(h1f[k0 + k], Wp1[(size_t)(k0 + k) * HH + j], a1);
    a1 = kred(a1) + bp1[j];
    if (s == 0) p1f[j] = fmaxf(a1, 0.f);
  }
  __syncthreads();
  if (tid < 192) {
    int jo = tid >> 2, so = tid & 3;   // 48 outputs x 4 splits
    float o = 0.f;
    int k0 = so * 64;
    #pragma unroll 8
    for (int k = 0; k < 64; ++k) o = fmaf(p1f[k0 + k], Wp2[(size_t)(k0 + k) * 48 + jo], o);
    o += __shfl_xor(o, 1, 64);
    o += __shfl_xor(o, 2, 64);
    if (so == 0) out[(size_t)b * 48 + jo] = o + bp2[jo];
  }
}

extern "C" void kernel_launch(void* const* d_in, const int* in_sizes, int n_in,
                              void* d_out, int out_size, void* d_ws, size_t ws_size,
                              hipStream_t stream) {
  const float* x    = (const float*)d_in[0];
  const float* mask = (const float*)d_in[1];
  const float* delta= (const float*)d_in[2];
  const float* xl   = (const float*)d_in[3];
  const int*   sidx = (const int*)d_in[4];
  const float* emb  = (const float*)d_in[5];
  const float* gx0  = (const float*)d_in[6];
  const float* gh0  = (const float*)d_in[7];
  const float* Wr0  = (const float*)d_in[8];
  const float* br0  = (const float*)d_in[9];
  const float* Wz0  = (const float*)d_in[10];
  const float* bz0  = (const float*)d_in[11];
  const float* Wh0  = (const float*)d_in[12];
  const float* bh0  = (const float*)d_in[13];
  // d_in[14]=gx1, d_in[15]=gh1: mathematically inert (layer1 delta==0)
  const float* Wr1  = (const float*)d_in[16];
  const float* br1  = (const float*)d_in[17];
  const float* Wz1  = (const float*)d_in[18];
  const float* bz1  = (const float*)d_in[19];
  const float* Wh1  = (const float*)d_in[20];
  const float* bh1  = (const float*)d_in[21];
  const float* Wp1  = (const float*)d_in[22];
  const float* bp1  = (const float*)d_in[23];
  const float* Wp2  = (const float*)d_in[24];
  const float* bp2  = (const float*)d_in[25];
  __half* PW = (__half*)d_ws;          // 1.33 MB used; re-packed every call
  float* out = (float*)d_out;

  hipLaunchKernelGGL(pack_weights, dim3((PACK_TOTAL + 255) / 256), dim3(256), 0, stream,
                     Wr0, Wz0, Wh0, Wr1, Wz1, Wh1, PW);
  hipLaunchKernelGGL(grud_fused, dim3(BB), dim3(1024), 0, stream,
                     x, mask, delta, xl, sidx, emb, gx0, gh0,
                     br0, bz0, bh0, br1, bz1, bh1, Wp1, bp1, Wp2, bp2, PW, out);
}

// Round 6
// 25630.035 us; speedup vs baseline: 1.1493x; 1.1493x over previous
//
#include <hip/hip_runtime.h>
#include <hip/hip_fp16.h>

// GRU-D 2-layer recurrent head, MI355X.
// Design R6 = R4 structure + (a) __launch_bounds__(1024,4) to unlock 128
// VGPRs/wave (R4 ran at 1 block/CU anyway; default bounds capped at 64 VGPR),
// (b) full phase unrolls so the COMPILER deepens the load window within its
// register budget (R5's hand-hoisted uint4 arrays forced >128 live VGPRs ->
// spill catastrophe: WRITE_SIZE 48KB->423MB, 29.5ms), (c) register prefetch
// of next-t inputs. Numerics identical to R4 (passed, absmax 4.9e-4).

#define BB  256
#define TT  512
#define DX  64
#define EE  32
#define DIN 96
#define HH  256

// packed half-weight offsets (in halves); region layout [K/32][256][4][8]
#define OFF_W0X_R 0        // K=96 regions: 3 segs * 8192
#define OFF_W0X_Z 24576
#define OFF_W0X_H 49152
#define OFF_W0H_R 73728    // K=256 regions: 8 segs * 8192
#define OFF_W0H_Z 139264
#define OFF_W0H_H 204800
#define OFF_W1X_R 270336
#define OFF_W1X_Z 335872
#define OFF_W1X_H 401408
#define OFF_W1H_R 466944
#define OFF_W1H_Z 532480
#define OFF_W1H_H 598016
#define PACK_TOTAL 663552  // halves = 1.33 MB

typedef _Float16 half2_t __attribute__((ext_vector_type(2)));

__global__ void pack_weights(const float* __restrict__ Wr0, const float* __restrict__ Wz0,
                             const float* __restrict__ Wh0, const float* __restrict__ Wr1,
                             const float* __restrict__ Wz1, const float* __restrict__ Wh1,
                             __half* __restrict__ dst) {
  int idx = blockIdx.x * blockDim.x + threadIdx.x;
  if (idx >= PACK_TOTAL) return;
  const float* src;
  int row0, local;
  if (idx < 73728) {                       // x-part of layer0: K=96
    int r = idx / 24576; local = idx % 24576;
    src = (r == 0) ? Wr0 : (r == 1) ? Wz0 : Wh0;
    row0 = 0;
  } else {
    int q = (idx - 73728) / 65536; local = (idx - 73728) % 65536;
    if (q < 3)      { src = (q == 0) ? Wr0 : (q == 1) ? Wz0 : Wh0; row0 = 96;  }
    else if (q < 6) { src = (q == 3) ? Wr1 : (q == 4) ? Wz1 : Wh1; row0 = 0;   }
    else            { src = (q == 6) ? Wr1 : (q == 7) ? Wz1 : Wh1; row0 = 256; }
  }
  // region layout: [seg][j:256][s:4][i:8]; source K-row = seg*32 + s*8 + i
  int seg = local >> 13;
  int rem = local & 8191;
  int j   = rem >> 5;
  int s   = (rem >> 3) & 3;
  int i   = rem & 7;
  int row = row0 + seg * 32 + s * 8 + i;
  dst[idx] = __float2half(src[(size_t)row * HH + j]);
}

__device__ __forceinline__ float dot8(uint4 w, uint4 v, float acc) {
#if __has_builtin(__builtin_amdgcn_fdot2)
  union { uint4 u; half2_t h[4]; } W, V;
  W.u = w; V.u = v;
  acc = __builtin_amdgcn_fdot2(W.h[0], V.h[0], acc, false);
  acc = __builtin_amdgcn_fdot2(W.h[1], V.h[1], acc, false);
  acc = __builtin_amdgcn_fdot2(W.h[2], V.h[2], acc, false);
  acc = __builtin_amdgcn_fdot2(W.h[3], V.h[3], acc, false);
#else
  union { unsigned u; __half2 h; } cw, cv;
  float2 wf, vf;
  cw.u = w.x; cv.u = v.x; wf = __half22float2(cw.h); vf = __half22float2(cv.h);
  acc = fmaf(wf.x, vf.x, acc); acc = fmaf(wf.y, vf.y, acc);
  cw.u = w.y; cv.u = v.y; wf = __half22float2(cw.h); vf = __half22float2(cv.h);
  acc = fmaf(wf.x, vf.x, acc); acc = fmaf(wf.y, vf.y, acc);
  cw.u = w.z; cv.u = v.z; wf = __half22float2(cw.h); vf = __half22float2(cv.h);
  acc = fmaf(wf.x, vf.x, acc); acc = fmaf(wf.y, vf.y, acc);
  cw.u = w.w; cv.u = v.w; wf = __half22float2(cw.h); vf = __half22float2(cv.h);
  acc = fmaf(wf.x, vf.x, acc); acc = fmaf(wf.y, vf.y, acc);
#endif
  return acc;
}

__device__ __forceinline__ float kred(float a) {   // combine 4 K-split partials
  a += __shfl_xor(a, 1, 64);
  a += __shfl_xor(a, 2, 64);
  return a;
}

__device__ __forceinline__ float sigm(float x) { return 1.f / (1.f + __expf(-x)); }

__global__ __launch_bounds__(1024, 4) void grud_fused(
    const float* __restrict__ x, const float* __restrict__ mask,
    const float* __restrict__ delta, const float* __restrict__ xl,
    const int* __restrict__ sidx, const float* __restrict__ emb,
    const float* __restrict__ gx0, const float* __restrict__ gh0,
    const float* __restrict__ br0, const float* __restrict__ bz0, const float* __restrict__ bh0,
    const float* __restrict__ br1, const float* __restrict__ bz1, const float* __restrict__ bh1,
    const float* __restrict__ Wp1, const float* __restrict__ bp1,
    const float* __restrict__ Wp2, const float* __restrict__ bp2,
    const __half* __restrict__ PW, float* __restrict__ out)
{
  const int b   = blockIdx.x;
  const int tid = threadIdx.x;
  const int j   = tid >> 2;      // hidden column 0..255
  const int s   = tid & 3;       // K-split 0..3
  const int s8  = s * 8;         // half-offset of this split's slice in a segment
  const int jb  = j * 4 + s;     // uint4 index within a segment

  __shared__ __align__(16) __half xfh[DIN];    // x_filled (fp16, for dots)
  __shared__ __align__(16) __half hdech[HH];   // h_decay * h0_prev
  __shared__ __align__(16) __half rhh[HH];     // r * h_dec (reused by both layers)
  __shared__ __align__(16) __half h0h[HH];
  __shared__ __align__(16) __half h1h[HH];
  __shared__ float h1f[HH];
  __shared__ float p1f[HH];
  __shared__ float sdel;

  const float brj0 = br0[j], bzj0 = bz0[j], bhj0 = bh0[j];
  const float brj1 = br1[j], bzj1 = bz1[j], bhj1 = bh1[j];
  const float gh0j = gh0[j];
  float gx0j = 0.f;
  if (tid < DX) gx0j = gx0[tid];

  if (tid < HH) { h0h[tid] = __float2half(0.f); h1h[tid] = __float2half(0.f); }
  if (tid < EE) xfh[DX + tid] = __float2half(emb[(size_t)sidx[b] * EE + tid]); // const over t
  float h0j = 0.f, h1j = 0.f;

  const size_t xoff = (size_t)b * TT * DX;
  const uint4* W0XR = reinterpret_cast<const uint4*>(PW + OFF_W0X_R);
  const uint4* W0XZ = reinterpret_cast<const uint4*>(PW + OFF_W0X_Z);
  const uint4* W0XH = reinterpret_cast<const uint4*>(PW + OFF_W0X_H);
  const uint4* W0HR = reinterpret_cast<const uint4*>(PW + OFF_W0H_R);
  const uint4* W0HZ = reinterpret_cast<const uint4*>(PW + OFF_W0H_Z);
  const uint4* W0HH = reinterpret_cast<const uint4*>(PW + OFF_W0H_H);
  const uint4* W1XR = reinterpret_cast<const uint4*>(PW + OFF_W1X_R);
  const uint4* W1XZ = reinterpret_cast<const uint4*>(PW + OFF_W1X_Z);
  const uint4* W1XH = reinterpret_cast<const uint4*>(PW + OFF_W1X_H);
  const uint4* W1HR = reinterpret_cast<const uint4*>(PW + OFF_W1H_R);
  const uint4* W1HZ = reinterpret_cast<const uint4*>(PW + OFF_W1H_Z);
  const uint4* W1HH = reinterpret_cast<const uint4*>(PW + OFF_W1H_H);

  // prefetch t=0 inputs into registers
  float xv = 0.f, mv = 0.f, dv = 0.f, xlv = 0.f;
  if (tid < DX) {
    size_t a = xoff + tid;
    xv = x[a]; mv = mask[a]; dv = delta[a]; xlv = xl[a];
  }
  __syncthreads();

  for (int t = 0; t < TT; ++t) {
    // ---- P0: x_filled (wave 0, from prefetched regs) + mean-delta scalar ----
    if (tid < DX) {
      float xd = __expf(-fmaxf(dv * gx0j, 0.f)) * xlv;
      xfh[tid] = __float2half(mv > 0.f ? xv : xd);
      float ssum = dv;
      #pragma unroll
      for (int o = 32; o > 0; o >>= 1) ssum += __shfl_down(ssum, o, 64);
      if (tid == 0) sdel = ssum * (1.f / 96.f);
    }
    __syncthreads();
    // ---- P1: h_dec = exp(-relu(sdel*gh0)) * h0 (redundant across s) ----
    float hd = __expf(-fmaxf(sdel * gh0j, 0.f));
    float hdecj = hd * h0j;
    if (s == 0) hdech[j] = __float2half(hdecj);
    __syncthreads();

    // ---- prefetch inputs for t+1 (independent; compiler schedules early) ----
    if (tid < DX && t + 1 < TT) {
      size_t a = xoff + (size_t)(t + 1) * DX + tid;
      xv = x[a]; mv = mask[a]; dv = delta[a]; xlv = xl[a];
    }

    // ---- P2: layer0 r,z pre-acts + x-part of h_tilde (full unroll) ----
    float ar = 0.f, az = 0.f, ah = 0.f;
    #pragma unroll
    for (int seg = 0; seg < 3; ++seg) {
      uint4 v = *reinterpret_cast<const uint4*>(xfh + seg * 32 + s8);
      int wi = seg * 1024 + jb;
      ar = dot8(W0XR[wi], v, ar);
      az = dot8(W0XZ[wi], v, az);
      ah = dot8(W0XH[wi], v, ah);
    }
    #pragma unroll
    for (int seg = 0; seg < 8; ++seg) {
      uint4 v = *reinterpret_cast<const uint4*>(hdech + seg * 32 + s8);
      int wi = seg * 1024 + jb;
      ar = dot8(W0HR[wi], v, ar);
      az = dot8(W0HZ[wi], v, az);
    }
    ar = kred(ar) + brj0;
    az = kred(az) + bzj0;
    float r = sigm(ar);
    float z = sigm(az);
    if (s == 0) rhh[j] = __float2half(r * hdecj);
    __syncthreads();
    // ---- P3: layer0 h_tilde, h0 update ----
    #pragma unroll
    for (int seg = 0; seg < 8; ++seg) {
      uint4 v = *reinterpret_cast<const uint4*>(rhh + seg * 32 + s8);
      ah = dot8(W0HH[seg * 1024 + jb], v, ah);
    }
    ah = kred(ah) + bhj0;
    float ht = tanhf(ah);
    h0j = (1.f - z) * hdecj + z * ht;
    if (s == 0) h0h[j] = __float2half(h0j);
    __syncthreads();
    // ---- P4: layer1 r,z pre-acts + h0-part of h_tilde ----
    float ar1 = 0.f, az1 = 0.f, ah1 = 0.f;
    #pragma unroll
    for (int seg = 0; seg < 8; ++seg) {
      uint4 v0 = *reinterpret_cast<const uint4*>(h0h + seg * 32 + s8);
      uint4 v1 = *reinterpret_cast<const uint4*>(h1h + seg * 32 + s8);
      int wi = seg * 1024 + jb;
      ar1 = dot8(W1XR[wi], v0, ar1);
      az1 = dot8(W1XZ[wi], v0, az1);
      ah1 = dot8(W1XH[wi], v0, ah1);
      ar1 = dot8(W1HR[wi], v1, ar1);
      az1 = dot8(W1HZ[wi], v1, az1);
    }
    ar1 = kred(ar1) + brj1;
    az1 = kred(az1) + bzj1;
    float r1 = sigm(ar1);
    float z1 = sigm(az1);
    if (s == 0) rhh[j] = __float2half(r1 * h1j);
    __syncthreads();
    // ---- P5: layer1 h_tilde, h1 update (no trailing barrier needed) ----
    #pragma unroll
    for (int seg = 0; seg < 8; ++seg) {
      uint4 v = *reinterpret_cast<const uint4*>(rhh + seg * 32 + s8);
      ah1 = dot8(W1HH[seg * 1024 + jb], v, ah1);
    }
    ah1 = kred(ah1) + bhj1;
    float ht1 = tanhf(ah1);
    h1j = (1.f - z1) * h1j + z1 * ht1;
    if (s == 0) h1h[j] = __float2half(h1j);
  }

  // ---- head: out = relu(h1 @ Wp1 + bp1) @ Wp2 + bp2, fp32, K-split too ----
  if (s == 0) h1f[j] = h1j;
  __syncthreads();
  {
    float a1 = 0.f;
    int k0 = s * 64;
    #pragma unroll 8
    for (int k = 0; k < 64; ++k) a1 = fmaf(h1f[k0 + k], Wp1[(size_t)(k0 + k) * HH + j], a1);
    a1 = kred(a1) + bp1[j];
    if (s == 0) p1f[j] = fmaxf(a1, 0.f);
  }
  __syncthreads();
  if (tid < 192) {
    int jo = tid >> 2, so = tid & 3;   // 48 outputs x 4 splits
    float o = 0.f;
    int k0 = so * 64;
    #pragma unroll 8
    for (int k = 0; k < 64; ++k) o = fmaf(p1f[k0 + k], Wp2[(size_t)(k0 + k) * 48 + jo], o);
    o += __shfl_xor(o, 1, 64);
    o += __shfl_xor(o, 2, 64);
    if (so == 0) out[(size_t)b * 48 + jo] = o + bp2[jo];
  }
}

extern "C" void kernel_launch(void* const* d_in, const int* in_sizes, int n_in,
                              void* d_out, int out_size, void* d_ws, size_t ws_size,
                              hipStream_t stream) {
  const float* x    = (const float*)d_in[0];
  const float* mask = (const float*)d_in[1];
  const float* delta= (const float*)d_in[2];
  const float* xl   = (const float*)d_in[3];
  const int*   sidx = (const int*)d_in[4];
  const float* emb  = (const float*)d_in[5];
  const float* gx0  = (const float*)d_in[6];
  const float* gh0  = (const float*)d_in[7];
  const float* Wr0  = (const float*)d_in[8];
  const float* br0  = (const float*)d_in[9];
  const float* Wz0  = (const float*)d_in[10];
  const float* bz0  = (const float*)d_in[11];
  const float* Wh0  = (const float*)d_in[12];
  const float* bh0  = (const float*)d_in[13];
  // d_in[14]=gx1, d_in[15]=gh1: mathematically inert (layer1 delta==0)
  const float* Wr1  = (const float*)d_in[16];
  const float* br1  = (const float*)d_in[17];
  const float* Wz1  = (const float*)d_in[18];
  const float* bz1  = (const float*)d_in[19];
  const float* Wh1  = (const float*)d_in[20];
  const float* bh1  = (const float*)d_in[21];
  const float* Wp1  = (const float*)d_in[22];
  const float* bp1  = (const float*)d_in[23];
  const float* Wp2  = (const float*)d_in[24];
  const float* bp2  = (const float*)d_in[25];
  __half* PW = (__half*)d_ws;          // 1.33 MB used; re-packed every call
  float* out = (float*)d_out;

  hipLaunchKernelGGL(pack_weights, dim3((PACK_TOTAL + 255) / 256), dim3(256), 0, stream,
                     Wr0, Wz0, Wh0, Wr1, Wz1, Wh1, PW);
  hipLaunchKernelGGL(grud_fused, dim3(BB), dim3(1024), 0, stream,
                     x, mask, delta, xl, sidx, emb, gx0, gh0,
                     br0, bz0, bh0, br1, bz1, bh1, Wp1, bp1, Wp2, bp2, PW, out);
}

// Round 7
// 5780.625 us; speedup vs baseline: 5.0959x; 4.4338x over previous
//
#include <hip/hip_runtime.h>
#include <hip/hip_fp16.h>

// GRU-D 2-layer recurrent head, MI355X.
// Design R7 = R4 EXACT structure (6.4ms known-good: unroll-4/2 chunks, 60 VGPR,
// no spill) + two minimal changes:
//  (a) amdgpu_waves_per_eu(4,4): force regalloc for 4 waves/SIMD -> 128 VGPR
//      budget. launch_bounds(1024,4) provably did NOT do this (R6: still 64
//      VGPR + spill). Full unrolls stay OUT (R5/R6: hoisted liveness > budget
//      -> 420MB scratch writes, 25-29ms).
//  (b) register prefetch of next-t inputs (off critical path).
// Numerics identical to R4 (passed, absmax 4.9e-4).

#define BB  256
#define TT  512
#define DX  64
#define EE  32
#define DIN 96
#define HH  256

// packed half-weight offsets (in halves); region layout [K/32][256][4][8]
#define OFF_W0X_R 0        // K=96 regions: 3 segs * 8192
#define OFF_W0X_Z 24576
#define OFF_W0X_H 49152
#define OFF_W0H_R 73728    // K=256 regions: 8 segs * 8192
#define OFF_W0H_Z 139264
#define OFF_W0H_H 204800
#define OFF_W1X_R 270336
#define OFF_W1X_Z 335872
#define OFF_W1X_H 401408
#define OFF_W1H_R 466944
#define OFF_W1H_Z 532480
#define OFF_W1H_H 598016
#define PACK_TOTAL 663552  // halves = 1.33 MB

typedef _Float16 half2_t __attribute__((ext_vector_type(2)));

__global__ void pack_weights(const float* __restrict__ Wr0, const float* __restrict__ Wz0,
                             const float* __restrict__ Wh0, const float* __restrict__ Wr1,
                             const float* __restrict__ Wz1, const float* __restrict__ Wh1,
                             __half* __restrict__ dst) {
  int idx = blockIdx.x * blockDim.x + threadIdx.x;
  if (idx >= PACK_TOTAL) return;
  const float* src;
  int row0, local;
  if (idx < 73728) {                       // x-part of layer0: K=96
    int r = idx / 24576; local = idx % 24576;
    src = (r == 0) ? Wr0 : (r == 1) ? Wz0 : Wh0;
    row0 = 0;
  } else {
    int q = (idx - 73728) / 65536; local = (idx - 73728) % 65536;
    if (q < 3)      { src = (q == 0) ? Wr0 : (q == 1) ? Wz0 : Wh0; row0 = 96;  }
    else if (q < 6) { src = (q == 3) ? Wr1 : (q == 4) ? Wz1 : Wh1; row0 = 0;   }
    else            { src = (q == 6) ? Wr1 : (q == 7) ? Wz1 : Wh1; row0 = 256; }
  }
  // region layout: [seg][j:256][s:4][i:8]; source K-row = seg*32 + s*8 + i
  int seg = local >> 13;
  int rem = local & 8191;
  int j   = rem >> 5;
  int s   = (rem >> 3) & 3;
  int i   = rem & 7;
  int row = row0 + seg * 32 + s * 8 + i;
  dst[idx] = __float2half(src[(size_t)row * HH + j]);
}

__device__ __forceinline__ float dot8(uint4 w, uint4 v, float acc) {
#if __has_builtin(__builtin_amdgcn_fdot2)
  union { uint4 u; half2_t h[4]; } W, V;
  W.u = w; V.u = v;
  acc = __builtin_amdgcn_fdot2(W.h[0], V.h[0], acc, false);
  acc = __builtin_amdgcn_fdot2(W.h[1], V.h[1], acc, false);
  acc = __builtin_amdgcn_fdot2(W.h[2], V.h[2], acc, false);
  acc = __builtin_amdgcn_fdot2(W.h[3], V.h[3], acc, false);
#else
  union { unsigned u; __half2 h; } cw, cv;
  float2 wf, vf;
  cw.u = w.x; cv.u = v.x; wf = __half22float2(cw.h); vf = __half22float2(cv.h);
  acc = fmaf(wf.x, vf.x, acc); acc = fmaf(wf.y, vf.y, acc);
  cw.u = w.y; cv.u = v.y; wf = __half22float2(cw.h); vf = __half22float2(cv.h);
  acc = fmaf(wf.x, vf.x, acc); acc = fmaf(wf.y, vf.y, acc);
  cw.u = w.z; cv.u = v.z; wf = __half22float2(cw.h); vf = __half22float2(cv.h);
  acc = fmaf(wf.x, vf.x, acc); acc = fmaf(wf.y, vf.y, acc);
  cw.u = w.w; cv.u = v.w; wf = __half22float2(cw.h); vf = __half22float2(cv.h);
  acc = fmaf(wf.x, vf.x, acc); acc = fmaf(wf.y, vf.y, acc);
#endif
  return acc;
}

__device__ __forceinline__ float kred(float a) {   // combine 4 K-split partials
  a += __shfl_xor(a, 1, 64);
  a += __shfl_xor(a, 2, 64);
  return a;
}

__device__ __forceinline__ float sigm(float x) { return 1.f / (1.f + __expf(-x)); }

__global__ __launch_bounds__(1024)
__attribute__((amdgpu_waves_per_eu(4, 4)))
void grud_fused(
    const float* __restrict__ x, const float* __restrict__ mask,
    const float* __restrict__ delta, const float* __restrict__ xl,
    const int* __restrict__ sidx, const float* __restrict__ emb,
    const float* __restrict__ gx0, const float* __restrict__ gh0,
    const float* __restrict__ br0, const float* __restrict__ bz0, const float* __restrict__ bh0,
    const float* __restrict__ br1, const float* __restrict__ bz1, const float* __restrict__ bh1,
    const float* __restrict__ Wp1, const float* __restrict__ bp1,
    const float* __restrict__ Wp2, const float* __restrict__ bp2,
    const __half* __restrict__ PW, float* __restrict__ out)
{
  const int b   = blockIdx.x;
  const int tid = threadIdx.x;
  const int j   = tid >> 2;      // hidden column 0..255
  const int s   = tid & 3;       // K-split 0..3
  const int s8  = s * 8;         // half-offset of this split's slice in a segment
  const int jb  = j * 4 + s;     // uint4 index within a segment

  __shared__ __align__(16) __half xfh[DIN];    // x_filled (fp16, for dots)
  __shared__ __align__(16) __half hdech[HH];   // h_decay * h0_prev
  __shared__ __align__(16) __half rhh[HH];     // r * h_dec (reused by both layers)
  __shared__ __align__(16) __half h0h[HH];
  __shared__ __align__(16) __half h1h[HH];
  __shared__ float h1f[HH];
  __shared__ float p1f[HH];
  __shared__ float sdel;

  const float brj0 = br0[j], bzj0 = bz0[j], bhj0 = bh0[j];
  const float brj1 = br1[j], bzj1 = bz1[j], bhj1 = bh1[j];
  const float gh0j = gh0[j];
  float gx0j = 0.f;
  if (tid < DX) gx0j = gx0[tid];

  if (tid < HH) { h0h[tid] = __float2half(0.f); h1h[tid] = __float2half(0.f); }
  if (tid < EE) xfh[DX + tid] = __float2half(emb[(size_t)sidx[b] * EE + tid]); // const over t
  float h0j = 0.f, h1j = 0.f;

  const size_t xoff = (size_t)b * TT * DX;
  const uint4* W0XR = reinterpret_cast<const uint4*>(PW + OFF_W0X_R);
  const uint4* W0XZ = reinterpret_cast<const uint4*>(PW + OFF_W0X_Z);
  const uint4* W0XH = reinterpret_cast<const uint4*>(PW + OFF_W0X_H);
  const uint4* W0HR = reinterpret_cast<const uint4*>(PW + OFF_W0H_R);
  const uint4* W0HZ = reinterpret_cast<const uint4*>(PW + OFF_W0H_Z);
  const uint4* W0HH = reinterpret_cast<const uint4*>(PW + OFF_W0H_H);
  const uint4* W1XR = reinterpret_cast<const uint4*>(PW + OFF_W1X_R);
  const uint4* W1XZ = reinterpret_cast<const uint4*>(PW + OFF_W1X_Z);
  const uint4* W1XH = reinterpret_cast<const uint4*>(PW + OFF_W1X_H);
  const uint4* W1HR = reinterpret_cast<const uint4*>(PW + OFF_W1H_R);
  const uint4* W1HZ = reinterpret_cast<const uint4*>(PW + OFF_W1H_Z);
  const uint4* W1HH = reinterpret_cast<const uint4*>(PW + OFF_W1H_H);

  // prefetch t=0 inputs into registers
  float xv = 0.f, mv = 0.f, dv = 0.f, xlv = 0.f;
  if (tid < DX) {
    size_t a = xoff + tid;
    xv = x[a]; mv = mask[a]; dv = delta[a]; xlv = xl[a];
  }
  __syncthreads();

  for (int t = 0; t < TT; ++t) {
    // ---- P0: x_filled (wave 0, from prefetched regs) + mean-delta scalar ----
    if (tid < DX) {
      float xd = __expf(-fmaxf(dv * gx0j, 0.f)) * xlv;
      xfh[tid] = __float2half(mv > 0.f ? xv : xd);
      float ssum = dv;
      #pragma unroll
      for (int o = 32; o > 0; o >>= 1) ssum += __shfl_down(ssum, o, 64);
      if (tid == 0) sdel = ssum * (1.f / 96.f);
    }
    __syncthreads();
    // ---- P1: h_dec = exp(-relu(sdel*gh0)) * h0 (redundant across s) ----
    float hd = __expf(-fmaxf(sdel * gh0j, 0.f));
    float hdecj = hd * h0j;
    if (s == 0) hdech[j] = __float2half(hdecj);
    __syncthreads();

    // ---- prefetch inputs for t+1 (independent; compiler schedules early) ----
    if (tid < DX && t + 1 < TT) {
      size_t a = xoff + (size_t)(t + 1) * DX + tid;
      xv = x[a]; mv = mask[a]; dv = delta[a]; xlv = xl[a];
    }

    // ---- P2: layer0 r,z pre-acts + x-part of h_tilde ----
    float ar = 0.f, az = 0.f, ah = 0.f;
    #pragma unroll
    for (int seg = 0; seg < 3; ++seg) {
      uint4 v = *reinterpret_cast<const uint4*>(xfh + seg * 32 + s8);
      int wi = seg * 1024 + jb;
      ar = dot8(W0XR[wi], v, ar);
      az = dot8(W0XZ[wi], v, az);
      ah = dot8(W0XH[wi], v, ah);
    }
    #pragma unroll 4
    for (int seg = 0; seg < 8; ++seg) {
      uint4 v = *reinterpret_cast<const uint4*>(hdech + seg * 32 + s8);
      int wi = seg * 1024 + jb;
      ar = dot8(W0HR[wi], v, ar);
      az = dot8(W0HZ[wi], v, az);
    }
    ar = kred(ar) + brj0;
    az = kred(az) + bzj0;
    float r = sigm(ar);
    float z = sigm(az);
    if (s == 0) rhh[j] = __float2half(r * hdecj);
    __syncthreads();
    // ---- P3: layer0 h_tilde, h0 update ----
    #pragma unroll 4
    for (int seg = 0; seg < 8; ++seg) {
      uint4 v = *reinterpret_cast<const uint4*>(rhh + seg * 32 + s8);
      ah = dot8(W0HH[seg * 1024 + jb], v, ah);
    }
    ah = kred(ah) + bhj0;
    float ht = tanhf(ah);
    h0j = (1.f - z) * hdecj + z * ht;
    if (s == 0) h0h[j] = __float2half(h0j);
    __syncthreads();
    // ---- P4: layer1 r,z pre-acts + h0-part of h_tilde ----
    float ar1 = 0.f, az1 = 0.f, ah1 = 0.f;
    #pragma unroll 2
    for (int seg = 0; seg < 8; ++seg) {
      uint4 v0 = *reinterpret_cast<const uint4*>(h0h + seg * 32 + s8);
      uint4 v1 = *reinterpret_cast<const uint4*>(h1h + seg * 32 + s8);
      int wi = seg * 1024 + jb;
      ar1 = dot8(W1XR[wi], v0, ar1);
      az1 = dot8(W1XZ[wi], v0, az1);
      ah1 = dot8(W1XH[wi], v0, ah1);
      ar1 = dot8(W1HR[wi], v1, ar1);
      az1 = dot8(W1HZ[wi], v1, az1);
    }
    ar1 = kred(ar1) + brj1;
    az1 = kred(az1) + bzj1;
    float r1 = sigm(ar1);
    float z1 = sigm(az1);
    if (s == 0) rhh[j] = __float2half(r1 * h1j);
    __syncthreads();
    // ---- P5: layer1 h_tilde, h1 update (no trailing barrier needed) ----
    #pragma unroll 4
    for (int seg = 0; seg < 8; ++seg) {
      uint4 v = *reinterpret_cast<const uint4*>(rhh + seg * 32 + s8);
      ah1 = dot8(W1HH[seg * 1024 + jb], v, ah1);
    }
    ah1 = kred(ah1) + bhj1;
    float ht1 = tanhf(ah1);
    h1j = (1.f - z1) * h1j + z1 * ht1;
    if (s == 0) h1h[j] = __float2half(h1j);
  }

  // ---- head: out = relu(h1 @ Wp1 + bp1) @ Wp2 + bp2, fp32, K-split too ----
  if (s == 0) h1f[j] = h1j;
  __syncthreads();
  {
    float a1 = 0.f;
    int k0 = s * 64;
    #pragma unroll 8
    for (int k = 0; k < 64; ++k) a1 = fmaf(h1f[k0 + k], Wp1[(size_t)(k0 + k) * HH + j], a1);
    a1 = kred(a1) + bp1[j];
    if (s == 0) p1f[j] = fmaxf(a1, 0.f);
  }
  __syncthreads();
  if (tid < 192) {
    int jo = tid >> 2, so = tid & 3;   // 48 outputs x 4 splits
    float o = 0.f;
    int k0 = so * 64;
    #pragma unroll 8
    for (int k = 0; k < 64; ++k) o = fmaf(p1f[k0 + k], Wp2[(size_t)(k0 + k) * 48 + jo], o);
    o += __shfl_xor(o, 1, 64);
    o += __shfl_xor(o, 2, 64);
    if (so == 0) out[(size_t)b * 48 + jo] = o + bp2[jo];
  }
}

extern "C" void kernel_launch(void* const* d_in, const int* in_sizes, int n_in,
                              void* d_out, int out_size, void* d_ws, size_t ws_size,
                              hipStream_t stream) {
  const float* x    = (const float*)d_in[0];
  const float* mask = (const float*)d_in[1];
  const float* delta= (const float*)d_in[2];
  const float* xl   = (const float*)d_in[3];
  const int*   sidx = (const int*)d_in[4];
  const float* emb  = (const float*)d_in[5];
  const float* gx0  = (const float*)d_in[6];
  const float* gh0  = (const float*)d_in[7];
  const float* Wr0  = (const float*)d_in[8];
  const float* br0  = (const float*)d_in[9];
  const float* Wz0  = (const float*)d_in[10];
  const float* bz0  = (const float*)d_in[11];
  const float* Wh0  = (const float*)d_in[12];
  const float* bh0  = (const float*)d_in[13];
  // d_in[14]=gx1, d_in[15]=gh1: mathematically inert (layer1 delta==0)
  const float* Wr1  = (const float*)d_in[16];
  const float* br1  = (const float*)d_in[17];
  const float* Wz1  = (const float*)d_in[18];
  const float* bz1  = (const float*)d_in[19];
  const float* Wh1  = (const float*)d_in[20];
  const float* bh1  = (const float*)d_in[21];
  const float* Wp1  = (const float*)d_in[22];
  const float* bp1  = (const float*)d_in[23];
  const float* Wp2  = (const float*)d_in[24];
  const float* bp2  = (const float*)d_in[25];
  __half* PW = (__half*)d_ws;          // 1.33 MB used; re-packed every call
  float* out = (float*)d_out;

  hipLaunchKernelGGL(pack_weights, dim3((PACK_TOTAL + 255) / 256), dim3(256), 0, stream,
                     Wr0, Wz0, Wh0, Wr1, Wz1, Wh1, PW);
  hipLaunchKernelGGL(grud_fused, dim3(BB), dim3(1024), 0, stream,
                     x, mask, delta, xl, sidx, emb, gx0, gh0,
                     br0, bz0, bh0, br1, bz1, bh1, Wp1, bp1, Wp2, bp2, PW, out);
}

// Round 9
// 5118.544 us; speedup vs baseline: 5.7550x; 1.1293x over previous
//
#include <hip/hip_runtime.h>
#include <hip/hip_fp16.h>

// GRU-D 2-layer recurrent head, MI355X.
// Design R9 = R8 resubmitted verbatim (R8 round failed on container
// acquisition; kernel never executed). Rationale unchanged:
// R7 (6.33ms rocprof) sits at ~80% of the aggregate-L2 streaming roofline;
// latency hiding exhausted (R4->R7 +1.5%). Lever: cut streamed bytes/step.
// Every thread re-reads the same 81 weight uint4s each of 512 steps; pin 22:
//  - W0HH region (8 uint4/thr) staged to LDS once (128KiB; P3 now LDS-only)
//  - W0XR/W0XZ (6) + W1HH (8) pinned in NAMED registers (no runtime-indexed
//    register arrays - those spill to scratch); P2 x-part and P5 hand-unrolled
//    to keep all indices compile-time.
// Streamed: 1.33 -> 0.97 MB/step. VGPR target ~116 of 128 (waves_per_eu 4,4).
// Watch-items: VGPR_Count (expect 100-124; 64 means inert), WRITE_SIZE
// (expect ~48KB; MBs mean spill -> revert reg-pinning next round).

#define BB  256
#define TT  512
#define DX  64
#define EE  32
#define DIN 96
#define HH  256

// packed half-weight offsets (in halves); region layout [K/32][256][4][8]
#define OFF_W0X_R 0        // K=96 regions: 3 segs * 8192
#define OFF_W0X_Z 24576
#define OFF_W0X_H 49152
#define OFF_W0H_R 73728    // K=256 regions: 8 segs * 8192
#define OFF_W0H_Z 139264
#define OFF_W0H_H 204800
#define OFF_W1X_R 270336
#define OFF_W1X_Z 335872
#define OFF_W1X_H 401408
#define OFF_W1H_R 466944
#define OFF_W1H_Z 532480
#define OFF_W1H_H 598016
#define PACK_TOTAL 663552  // halves = 1.33 MB

typedef _Float16 half2_t __attribute__((ext_vector_type(2)));

__global__ void pack_weights(const float* __restrict__ Wr0, const float* __restrict__ Wz0,
                             const float* __restrict__ Wh0, const float* __restrict__ Wr1,
                             const float* __restrict__ Wz1, const float* __restrict__ Wh1,
                             __half* __restrict__ dst) {
  int idx = blockIdx.x * blockDim.x + threadIdx.x;
  if (idx >= PACK_TOTAL) return;
  const float* src;
  int row0, local;
  if (idx < 73728) {                       // x-part of layer0: K=96
    int r = idx / 24576; local = idx % 24576;
    src = (r == 0) ? Wr0 : (r == 1) ? Wz0 : Wh0;
    row0 = 0;
  } else {
    int q = (idx - 73728) / 65536; local = (idx - 73728) % 65536;
    if (q < 3)      { src = (q == 0) ? Wr0 : (q == 1) ? Wz0 : Wh0; row0 = 96;  }
    else if (q < 6) { src = (q == 3) ? Wr1 : (q == 4) ? Wz1 : Wh1; row0 = 0;   }
    else            { src = (q == 6) ? Wr1 : (q == 7) ? Wz1 : Wh1; row0 = 256; }
  }
  // region layout: [seg][j:256][s:4][i:8]; source K-row = seg*32 + s*8 + i
  int seg = local >> 13;
  int rem = local & 8191;
  int j   = rem >> 5;
  int s   = (rem >> 3) & 3;
  int i   = rem & 7;
  int row = row0 + seg * 32 + s * 8 + i;
  dst[idx] = __float2half(src[(size_t)row * HH + j]);
}

__device__ __forceinline__ float dot8(uint4 w, uint4 v, float acc) {
#if __has_builtin(__builtin_amdgcn_fdot2)
  union { uint4 u; half2_t h[4]; } W, V;
  W.u = w; V.u = v;
  acc = __builtin_amdgcn_fdot2(W.h[0], V.h[0], acc, false);
  acc = __builtin_amdgcn_fdot2(W.h[1], V.h[1], acc, false);
  acc = __builtin_amdgcn_fdot2(W.h[2], V.h[2], acc, false);
  acc = __builtin_amdgcn_fdot2(W.h[3], V.h[3], acc, false);
#else
  union { unsigned u; __half2 h; } cw, cv;
  float2 wf, vf;
  cw.u = w.x; cv.u = v.x; wf = __half22float2(cw.h); vf = __half22float2(cv.h);
  acc = fmaf(wf.x, vf.x, acc); acc = fmaf(wf.y, vf.y, acc);
  cw.u = w.y; cv.u = v.y; wf = __half22float2(cw.h); vf = __half22float2(cv.h);
  acc = fmaf(wf.x, vf.x, acc); acc = fmaf(wf.y, vf.y, acc);
  cw.u = w.z; cv.u = v.z; wf = __half22float2(cw.h); vf = __half22float2(cv.h);
  acc = fmaf(wf.x, vf.x, acc); acc = fmaf(wf.y, vf.y, acc);
  cw.u = w.w; cv.u = v.w; wf = __half22float2(cw.h); vf = __half22float2(cv.h);
  acc = fmaf(wf.x, vf.x, acc); acc = fmaf(wf.y, vf.y, acc);
#endif
  return acc;
}

__device__ __forceinline__ float kred(float a) {   // combine 4 K-split partials
  a += __shfl_xor(a, 1, 64);
  a += __shfl_xor(a, 2, 64);
  return a;
}

__device__ __forceinline__ float sigm(float x) { return 1.f / (1.f + __expf(-x)); }

__global__ __launch_bounds__(1024)
__attribute__((amdgpu_waves_per_eu(4, 4)))
void grud_fused(
    const float* __restrict__ x, const float* __restrict__ mask,
    const float* __restrict__ delta, const float* __restrict__ xl,
    const int* __restrict__ sidx, const float* __restrict__ emb,
    const float* __restrict__ gx0, const float* __restrict__ gh0,
    const float* __restrict__ br0, const float* __restrict__ bz0, const float* __restrict__ bh0,
    const float* __restrict__ br1, const float* __restrict__ bz1, const float* __restrict__ bh1,
    const float* __restrict__ Wp1, const float* __restrict__ bp1,
    const float* __restrict__ Wp2, const float* __restrict__ bp2,
    const __half* __restrict__ PW, float* __restrict__ out)
{
  const int b   = blockIdx.x;
  const int tid = threadIdx.x;
  const int j   = tid >> 2;      // hidden column 0..255
  const int s   = tid & 3;       // K-split 0..3
  const int s8  = s * 8;         // half-offset of this split's slice in a segment
  const int jb  = j * 4 + s;     // uint4 index within a segment

  __shared__ __align__(16) uint4 wlds[8192];   // 128 KiB: W0HH resident in LDS
  __shared__ __align__(16) __half xfh[DIN];    // x_filled (fp16, for dots)
  __shared__ __align__(16) __half hdech[HH];   // h_decay * h0_prev
  __shared__ __align__(16) __half rhh[HH];     // r * h_dec (reused by both layers)
  __shared__ __align__(16) __half h0h[HH];
  __shared__ __align__(16) __half h1h[HH];
  __shared__ float h1f[HH];
  __shared__ float p1f[HH];
  __shared__ float sdel;

  const float brj0 = br0[j], bzj0 = bz0[j], bhj0 = bh0[j];
  const float brj1 = br1[j], bzj1 = bz1[j], bhj1 = bh1[j];
  const float gh0j = gh0[j];
  float gx0j = 0.f;
  if (tid < DX) gx0j = gx0[tid];

  if (tid < HH) { h0h[tid] = __float2half(0.f); h1h[tid] = __float2half(0.f); }
  if (tid < EE) xfh[DX + tid] = __float2half(emb[(size_t)sidx[b] * EE + tid]); // const over t
  float h0j = 0.f, h1j = 0.f;

  const size_t xoff = (size_t)b * TT * DX;
  const uint4* W0XR = reinterpret_cast<const uint4*>(PW + OFF_W0X_R);
  const uint4* W0XZ = reinterpret_cast<const uint4*>(PW + OFF_W0X_Z);
  const uint4* W0XH = reinterpret_cast<const uint4*>(PW + OFF_W0X_H);
  const uint4* W0HR = reinterpret_cast<const uint4*>(PW + OFF_W0H_R);
  const uint4* W0HZ = reinterpret_cast<const uint4*>(PW + OFF_W0H_Z);
  const uint4* W0HH = reinterpret_cast<const uint4*>(PW + OFF_W0H_H);
  const uint4* W1XR = reinterpret_cast<const uint4*>(PW + OFF_W1X_R);
  const uint4* W1XZ = reinterpret_cast<const uint4*>(PW + OFF_W1X_Z);
  const uint4* W1XH = reinterpret_cast<const uint4*>(PW + OFF_W1X_H);
  const uint4* W1HR = reinterpret_cast<const uint4*>(PW + OFF_W1H_R);
  const uint4* W1HZ = reinterpret_cast<const uint4*>(PW + OFF_W1H_Z);
  const uint4* W1HH = reinterpret_cast<const uint4*>(PW + OFF_W1H_H);

  // ---- stage W0HH into LDS (once) ----
  #pragma unroll 2
  for (int seg = 0; seg < 8; ++seg) wlds[seg * 1024 + jb] = W0HH[seg * 1024 + jb];

  // ---- pin small weight set in NAMED registers (compile-time indices only) ----
  const uint4 wxr0 = W0XR[jb], wxr1 = W0XR[1024 + jb], wxr2 = W0XR[2048 + jb];
  const uint4 wxz0 = W0XZ[jb], wxz1 = W0XZ[1024 + jb], wxz2 = W0XZ[2048 + jb];
  const uint4 whh0 = W1HH[jb],            whh1 = W1HH[1024 + jb];
  const uint4 whh2 = W1HH[2 * 1024 + jb], whh3 = W1HH[3 * 1024 + jb];
  const uint4 whh4 = W1HH[4 * 1024 + jb], whh5 = W1HH[5 * 1024 + jb];
  const uint4 whh6 = W1HH[6 * 1024 + jb], whh7 = W1HH[7 * 1024 + jb];

  // prefetch t=0 inputs into registers
  float xv = 0.f, mv = 0.f, dv = 0.f, xlv = 0.f;
  if (tid < DX) {
    size_t a = xoff + tid;
    xv = x[a]; mv = mask[a]; dv = delta[a]; xlv = xl[a];
  }
  __syncthreads();

  for (int t = 0; t < TT; ++t) {
    // ---- P0: x_filled (wave 0, from prefetched regs) + mean-delta scalar ----
    if (tid < DX) {
      float xd = __expf(-fmaxf(dv * gx0j, 0.f)) * xlv;
      xfh[tid] = __float2half(mv > 0.f ? xv : xd);
      float ssum = dv;
      #pragma unroll
      for (int o = 32; o > 0; o >>= 1) ssum += __shfl_down(ssum, o, 64);
      if (tid == 0) sdel = ssum * (1.f / 96.f);
    }
    __syncthreads();
    // ---- P1: h_dec = exp(-relu(sdel*gh0)) * h0 (redundant across s) ----
    float hd = __expf(-fmaxf(sdel * gh0j, 0.f));
    float hdecj = hd * h0j;
    if (s == 0) hdech[j] = __float2half(hdecj);
    __syncthreads();

    // ---- prefetch inputs for t+1 (independent; compiler schedules early) ----
    if (tid < DX && t + 1 < TT) {
      size_t a = xoff + (size_t)(t + 1) * DX + tid;
      xv = x[a]; mv = mask[a]; dv = delta[a]; xlv = xl[a];
    }

    // ---- P2: layer0 r,z pre-acts + x-part of h_tilde ----
    float ar = 0.f, az = 0.f, ah = 0.f;
    {  // x-part, hand-unrolled: R,Z from pinned regs; H streamed
      uint4 v0 = *reinterpret_cast<const uint4*>(xfh + s8);
      uint4 v1 = *reinterpret_cast<const uint4*>(xfh + 32 + s8);
      uint4 v2 = *reinterpret_cast<const uint4*>(xfh + 64 + s8);
      ar = dot8(wxr0, v0, ar); az = dot8(wxz0, v0, az); ah = dot8(W0XH[jb], v0, ah);
      ar = dot8(wxr1, v1, ar); az = dot8(wxz1, v1, az); ah = dot8(W0XH[1024 + jb], v1, ah);
      ar = dot8(wxr2, v2, ar); az = dot8(wxz2, v2, az); ah = dot8(W0XH[2048 + jb], v2, ah);
    }
    #pragma unroll 4
    for (int seg = 0; seg < 8; ++seg) {
      uint4 v = *reinterpret_cast<const uint4*>(hdech + seg * 32 + s8);
      int wi = seg * 1024 + jb;
      ar = dot8(W0HR[wi], v, ar);
      az = dot8(W0HZ[wi], v, az);
    }
    ar = kred(ar) + brj0;
    az = kred(az) + bzj0;
    float r = sigm(ar);
    float z = sigm(az);
    if (s == 0) rhh[j] = __float2half(r * hdecj);
    __syncthreads();
    // ---- P3: layer0 h_tilde from LDS-resident W0HH (no global loads) ----
    #pragma unroll 4
    for (int seg = 0; seg < 8; ++seg) {
      uint4 v = *reinterpret_cast<const uint4*>(rhh + seg * 32 + s8);
      ah = dot8(wlds[seg * 1024 + jb], v, ah);
    }
    ah = kred(ah) + bhj0;
    float ht = tanhf(ah);
    h0j = (1.f - z) * hdecj + z * ht;
    if (s == 0) h0h[j] = __float2half(h0j);
    __syncthreads();
    // ---- P4: layer1 r,z pre-acts + h0-part of h_tilde (streamed) ----
    float ar1 = 0.f, az1 = 0.f, ah1 = 0.f;
    #pragma unroll 2
    for (int seg = 0; seg < 8; ++seg) {
      uint4 v0 = *reinterpret_cast<const uint4*>(h0h + seg * 32 + s8);
      uint4 v1 = *reinterpret_cast<const uint4*>(h1h + seg * 32 + s8);
      int wi = seg * 1024 + jb;
      ar1 = dot8(W1XR[wi], v0, ar1);
      az1 = dot8(W1XZ[wi], v0, az1);
      ah1 = dot8(W1XH[wi], v0, ah1);
      ar1 = dot8(W1HR[wi], v1, ar1);
      az1 = dot8(W1HZ[wi], v1, az1);
    }
    ar1 = kred(ar1) + brj1;
    az1 = kred(az1) + bzj1;
    float r1 = sigm(ar1);
    float z1 = sigm(az1);
    if (s == 0) rhh[j] = __float2half(r1 * h1j);
    __syncthreads();
    // ---- P5: layer1 h_tilde from register-resident W1HH (no loads at all) ----
    ah1 = dot8(whh0, *reinterpret_cast<const uint4*>(rhh + 0 * 32 + s8), ah1);
    ah1 = dot8(whh1, *reinterpret_cast<const uint4*>(rhh + 1 * 32 + s8), ah1);
    ah1 = dot8(whh2, *reinterpret_cast<const uint4*>(rhh + 2 * 32 + s8), ah1);
    ah1 = dot8(whh3, *reinterpret_cast<const uint4*>(rhh + 3 * 32 + s8), ah1);
    ah1 = dot8(whh4, *reinterpret_cast<const uint4*>(rhh + 4 * 32 + s8), ah1);
    ah1 = dot8(whh5, *reinterpret_cast<const uint4*>(rhh + 5 * 32 + s8), ah1);
    ah1 = dot8(whh6, *reinterpret_cast<const uint4*>(rhh + 6 * 32 + s8), ah1);
    ah1 = dot8(whh7, *reinterpret_cast<const uint4*>(rhh + 7 * 32 + s8), ah1);
    ah1 = kred(ah1) + bhj1;
    float ht1 = tanhf(ah1);
    h1j = (1.f - z1) * h1j + z1 * ht1;
    if (s == 0) h1h[j] = __float2half(h1j);
  }

  // ---- head: out = relu(h1 @ Wp1 + bp1) @ Wp2 + bp2, fp32, K-split too ----
  if (s == 0) h1f[j] = h1j;
  __syncthreads();
  {
    float a1 = 0.f;
    int k0 = s * 64;
    #pragma unroll 8
    for (int k = 0; k < 64; ++k) a1 = fmaf(h1f[k0 + k], Wp1[(size_t)(k0 + k) * HH + j], a1);
    a1 = kred(a1) + bp1[j];
    if (s == 0) p1f[j] = fmaxf(a1, 0.f);
  }
  __syncthreads();
  if (tid < 192) {
    int jo = tid >> 2, so = tid & 3;   // 48 outputs x 4 splits
    float o = 0.f;
    int k0 = so * 64;
    #pragma unroll 8
    for (int k = 0; k < 64; ++k) o = fmaf(p1f[k0 + k], Wp2[(size_t)(k0 + k) * 48 + jo], o);
    o += __shfl_xor(o, 1, 64);
    o += __shfl_xor(o, 2, 64);
    if (so == 0) out[(size_t)b * 48 + jo] = o + bp2[jo];
  }
}

extern "C" void kernel_launch(void* const* d_in, const int* in_sizes, int n_in,
                              void* d_out, int out_size, void* d_ws, size_t ws_size,
                              hipStream_t stream) {
  const float* x    = (const float*)d_in[0];
  const float* mask = (const float*)d_in[1];
  const float* delta= (const float*)d_in[2];
  const float* xl   = (const float*)d_in[3];
  const int*   sidx = (const int*)d_in[4];
  const float* emb  = (const float*)d_in[5];
  const float* gx0  = (const float*)d_in[6];
  const float* gh0  = (const float*)d_in[7];
  const float* Wr0  = (const float*)d_in[8];
  const float* br0  = (const float*)d_in[9];
  const float* Wz0  = (const float*)d_in[10];
  const float* bz0  = (const float*)d_in[11];
  const float* Wh0  = (const float*)d_in[12];
  const float* bh0  = (const float*)d_in[13];
  // d_in[14]=gx1, d_in[15]=gh1: mathematically inert (layer1 delta==0)
  const float* Wr1  = (const float*)d_in[16];
  const float* br1  = (const float*)d_in[17];
  const float* Wz1  = (const float*)d_in[18];
  const float* bz1  = (const float*)d_in[19];
  const float* Wh1  = (const float*)d_in[20];
  const float* bh1  = (const float*)d_in[21];
  const float* Wp1  = (const float*)d_in[22];
  const float* bp1  = (const float*)d_in[23];
  const float* Wp2  = (const float*)d_in[24];
  const float* bp2  = (const float*)d_in[25];
  __half* PW = (__half*)d_ws;          // 1.33 MB used; re-packed every call
  float* out = (float*)d_out;

  hipLaunchKernelGGL(pack_weights, dim3((PACK_TOTAL + 255) / 256), dim3(256), 0, stream,
                     Wr0, Wz0, Wh0, Wr1, Wz1, Wh1, PW);
  hipLaunchKernelGGL(grud_fused, dim3(BB), dim3(1024), 0, stream,
                     x, mask, delta, xl, sidx, emb, gx0, gh0,
                     br0, bz0, bh0, br1, bz1, bh1, Wp1, bp1, Wp2, bp2, PW, out);
}